// Round 3
// baseline (190.432 us; speedup 1.0000x reference)
//
#include <hip/hip_runtime.h>

// KL( N(pm, ps^2) || N(qm, qs^2) ) over [32,128,32,64], sum/(B*L).
// kl_elem = 0.5*(r^2 + d^2 - 1) - log(r),  r = ps/qs, d = (qm-pm)/qs.
//
// Evidence ledger:
//  R8 (prev session): nt loads, deep-32 -> partial 35.6us (3.77 TB/s read). BEST.
//  R9: +occupancy (4 blocks/CU) -> null. Residency not binding.
//  R10: cached loads -> 43-47us, and L3-warm replays (hbm_bytes~0) STILL 42us.
//    => limiter is the read-RETURN path (~4 TB/s pure-read ceiling, per-XCD
//       round-trip tracking), not HBM, not occupancy, not cache home tier.
//       Writes (fills) hit 6.5 TB/s because they are posted; reads can't.
//  R11 (this round): nt restored (best-known read path); fuse the final
//    reduction into the partial kernel via last-block pattern to remove the
//    second launch + gap. Counter zeroed by an 8-byte hipMemsetAsync.

constexpr int TOTAL  = 32 * 128 * 32 * 64;   // 8388608 elements
constexpr int N4     = TOTAL / 4;            // 2097152 float4 per array
constexpr int BLOCK  = 256;
constexpr int GRID   = 1024;
constexpr int TILE4  = N4 / GRID;            // 2048 float4 per array per block
constexpr int PT     = TILE4 / BLOCK;        // 8 batches per thread
constexpr int CHUNK  = 4;                    // batches per chunk
constexpr int NCHUNK = PT / CHUNK;           // 2 chunks
constexpr float INV_BL = 1.0f / (32.0f * 128.0f);

static_assert(PT == 8 && NCHUNK == 2, "depth-8 per-thread as 2x depth-4, exact");

typedef float f4 __attribute__((ext_vector_type(4)));

__device__ __forceinline__ f4 ntload(const float4* p) {
    return __builtin_nontemporal_load((const f4*)p);
}

__device__ __forceinline__ float kl_elem(float a, float b, float c, float d) {
    float inv = __builtin_amdgcn_rcpf(d);     // v_rcp_f32, ~1ulp (tol is 2%)
    float r   = b * inv;
    float df  = (c - a) * inv;
    return 0.5f * (r * r + df * df - 1.0f) - __logf(r);
}

__device__ __forceinline__ float kl_4(f4 a, f4 b, f4 c, f4 d) {
    return (kl_elem(a.x, b.x, c.x, d.x) + kl_elem(a.y, b.y, c.y, d.y))
         + (kl_elem(a.z, b.z, c.z, d.z) + kl_elem(a.w, b.w, c.w, d.w));
}

// One chunk: issue 16 nt loads (4 arrays x depth-4), fence, consume.
__device__ __forceinline__ float chunk_accum(
    const float4* __restrict__ pm, const float4* __restrict__ ps,
    const float4* __restrict__ qm, const float4* __restrict__ qs,
    int base)
{
    f4 A[CHUNK], Bv[CHUNK], C[CHUNK], Dv[CHUNK];
    #pragma unroll
    for (int j = 0; j < CHUNK; ++j) {
        const int i = base + j * BLOCK;
        A[j]  = ntload(pm + i);
        Bv[j] = ntload(ps + i);
        C[j]  = ntload(qm + i);
        Dv[j] = ntload(qs + i);
    }
    __builtin_amdgcn_sched_barrier(0);   // loads stay issued above
    float accA = kl_4(A[0], Bv[0], C[0], Dv[0]) + kl_4(A[2], Bv[2], C[2], Dv[2]);
    float accB = kl_4(A[1], Bv[1], C[1], Dv[1]) + kl_4(A[3], Bv[3], C[3], Dv[3]);
    __builtin_amdgcn_sched_barrier(0);   // next chunk's loads stay below
    return accA + accB;
}

// ws layout: ws[0..GRID) = per-block partials; ws[GRID] = arrival counter
// (counter zeroed by hipMemsetAsync in kernel_launch each iteration).
__global__ __launch_bounds__(BLOCK, 4) void kl_fused_kernel(
    const float4* __restrict__ pm, const float4* __restrict__ ps,
    const float4* __restrict__ qm, const float4* __restrict__ qs,
    float* __restrict__ ws, float* __restrict__ out)
{
    const int tbase = blockIdx.x * TILE4 + threadIdx.x;

    float acc = 0.0f;
    #pragma unroll
    for (int c = 0; c < NCHUNK; ++c)
        acc += chunk_accum(pm, ps, qm, qs, tbase + c * (CHUNK * BLOCK));

    // wave-64 reduction
    #pragma unroll
    for (int off = 32; off > 0; off >>= 1)
        acc += __shfl_down(acc, off, 64);

    __shared__ float smem[BLOCK / 64];
    __shared__ unsigned s_old;
    const int lane = threadIdx.x & 63;
    const int wid  = threadIdx.x >> 6;
    if (lane == 0) smem[wid] = acc;
    __syncthreads();

    if (threadIdx.x == 0) {
        float t = 0.0f;
        #pragma unroll
        for (int w = 0; w < BLOCK / 64; ++w) t += smem[w];
        // publish partial (agent scope: visible across XCD L2s), then arrive.
        __hip_atomic_store(&ws[blockIdx.x], t, __ATOMIC_RELAXED,
                           __HIP_MEMORY_SCOPE_AGENT);
        unsigned* cnt = (unsigned*)(ws + GRID);
        s_old = __hip_atomic_fetch_add(cnt, 1u, __ATOMIC_ACQ_REL,
                                       __HIP_MEMORY_SCOPE_AGENT);
    }
    __syncthreads();

    if (s_old == GRID - 1) {
        // last-arriving block: all partials are published; reduce them.
        float a = 0.0f;
        for (int i = threadIdx.x; i < GRID; i += BLOCK)
            a += __hip_atomic_load(&ws[i], __ATOMIC_RELAXED,
                                   __HIP_MEMORY_SCOPE_AGENT);

        #pragma unroll
        for (int off = 32; off > 0; off >>= 1)
            a += __shfl_down(a, off, 64);

        __shared__ float smem2[BLOCK / 64];
        if (lane == 0) smem2[wid] = a;
        __syncthreads();

        if (threadIdx.x == 0) {
            float t = 0.0f;
            #pragma unroll
            for (int w = 0; w < BLOCK / 64; ++w) t += smem2[w];
            out[0] = t * INV_BL;
        }
    }
}

extern "C" void kernel_launch(void* const* d_in, const int* in_sizes, int n_in,
                              void* d_out, int out_size, void* d_ws, size_t ws_size,
                              hipStream_t stream) {
    const float4* pm = (const float4*)d_in[0];  // prior_mu
    const float4* ps = (const float4*)d_in[1];  // prior_sigma
    const float4* qm = (const float4*)d_in[2];  // post_mu
    const float4* qs = (const float4*)d_in[3];  // post_sigma
    float* ws  = (float*)d_ws;                  // GRID partials + 1 counter
    float* out = (float*)d_out;

    // Zero only the arrival counter (8B-aligned 4B region), stream-ordered.
    hipMemsetAsync((char*)d_ws + GRID * sizeof(float), 0, sizeof(unsigned),
                   stream);
    kl_fused_kernel<<<GRID, BLOCK, 0, stream>>>(pm, ps, qm, qs, ws, out);
}

// Round 6
// 151.276 us; speedup vs baseline: 1.2588x; 1.2588x over previous
//
#include <hip/hip_runtime.h>

// KL( N(pm, ps^2) || N(qm, qs^2) ) over [32,128,32,64], sum/(B*L).
// kl_elem = 0.5*(r^2 + d^2 - 1) - log(r),  r = ps/qs, d = (qm-pm)/qs.
//
// Evidence ledger:
//  R8: nt VGPR-loads, deep-32 -> partial 35.6us (3.77 TB/s). Best so far.
//  R9: occupancy 3->4 blocks/CU -> null. Residency not binding.
//  R10: cached loads -> 43-47us; L2/L3-WARM replays (hbm~0) still 42us
//       => VGPR-return read path caps ~3.2-3.8 TB/s regardless of tier.
//  R11: last-block fusion -> +38us (serialized same-address atomic tail).
//  R12/R13: global_load_lds + asm-volatile counted vmcnt + no barriers ->
//       container died twice, twice. Suspect kernel-induced GPU wedge;
//       that exact combination is retired.
//  R14 (this round): SAME path theory, m97-PROVEN structure: global_load_lds
//       + LDS double buffer + __syncthreads (compiler emits the vmcnt(0)
//       drain before s_barrier). No inline asm anywhere. Each wave stages
//       and consumes only its own LDS region; overlap via TLP (5 blocks/CU
//       at 32KB LDS). Also disambiguates: if THIS fails, it's infra.

constexpr int TOTAL  = 32 * 128 * 32 * 64;   // 8388608 elements
constexpr int N4     = TOTAL / 4;            // 2097152 float4 per array
constexpr int BLOCK  = 256;
constexpr int GRID   = 1024;
constexpr int TILE4  = N4 / GRID;            // 2048 float4 per array per block
constexpr int CH4    = 256;                  // float4 per chunk per array (block-wide)
constexpr int NCH    = TILE4 / CH4;          // 8 chunks
constexpr float INV_BL = 1.0f / (32.0f * 128.0f);

static_assert(NCH == 8, "8 chunks, exact");

typedef float f4 __attribute__((ext_vector_type(4)));

// global(as1) -> LDS(as3) DMA, 16B per lane. LDS dest is the wave-uniform
// base (HW adds lane*16); global src is per-lane. Size must be literal 16.
__device__ __forceinline__ void stage16(const float4* g, const float4* l) {
    __builtin_amdgcn_global_load_lds(
        (const __attribute__((address_space(1))) void*)g,
        (__attribute__((address_space(3))) void*)l,
        16, 0, 0);
}

__device__ __forceinline__ float kl_elem(float a, float b, float c, float d) {
    float inv = __builtin_amdgcn_rcpf(d);     // v_rcp_f32, ~1ulp (tol is 2%)
    float r   = b * inv;
    float df  = (c - a) * inv;
    return 0.5f * (r * r + df * df - 1.0f) - __logf(r);
}

__device__ __forceinline__ float kl_4(f4 a, f4 b, f4 c, f4 d) {
    return (kl_elem(a.x, b.x, c.x, d.x) + kl_elem(a.y, b.y, c.y, d.y))
         + (kl_elem(a.z, b.z, c.z, d.z) + kl_elem(a.w, b.w, c.w, d.w));
}

__global__ __launch_bounds__(BLOCK) void kl_partial_kernel(
    const float4* __restrict__ pm, const float4* __restrict__ ps,
    const float4* __restrict__ qm, const float4* __restrict__ qs,
    float* __restrict__ partial)
{
    __shared__ float4 lds[2][4][CH4];        // 2 x 16 KB double buffer

    const int tid  = threadIdx.x;
    const int lane = tid & 63;
    const int w    = tid >> 6;               // wave id (wave-uniform)
    const int gbase = blockIdx.x * TILE4;    // block's float4 base index

    // Wave w stages float4 [c*CH4 + w*64, +64) of each array into
    // lds[b][arr][w*64 .. w*64+64) -- exactly what its own lanes consume.
#define STAGE(c, b) do {                                                   \
        const int idx_ = gbase + (c) * CH4 + w * 64 + lane;                \
        stage16(pm + idx_, &lds[(b)][0][w * 64]);                          \
        stage16(ps + idx_, &lds[(b)][1][w * 64]);                          \
        stage16(qm + idx_, &lds[(b)][2][w * 64]);                          \
        stage16(qs + idx_, &lds[(b)][3][w * 64]);                          \
    } while (0)

    float acc = 0.0f;
    STAGE(0, 0);                             // prologue: chunk 0 -> buf 0

    #pragma unroll
    for (int c = 0; c < NCH; ++c) {
        const int buf = c & 1;
        if (c + 1 < NCH)
            STAGE(c + 1, (c + 1) & 1);       // issue next chunk's DMA
        // Compiler emits s_waitcnt vmcnt(0) before s_barrier: all issued
        // DMA (chunk c, and the c+1 prefetch) has landed in LDS.
        __syncthreads();

        const f4 a  = *(const f4*)&lds[buf][0][tid];
        const f4 b  = *(const f4*)&lds[buf][1][tid];
        const f4 cc = *(const f4*)&lds[buf][2][tid];
        const f4 d  = *(const f4*)&lds[buf][3][tid];
        acc += kl_4(a, b, cc, d);

        // Keep next iteration's STAGE from hoisting above these ds_reads
        // (WAR on lds[buf]); compile-time fence only.
        __builtin_amdgcn_sched_barrier(0);
    }
#undef STAGE

    // wave-64 reduction
    #pragma unroll
    for (int off = 32; off > 0; off >>= 1)
        acc += __shfl_down(acc, off, 64);

    __shared__ float smem[BLOCK / 64];
    if (lane == 0) smem[w] = acc;
    __syncthreads();

    if (tid == 0) {
        float t = 0.0f;
        #pragma unroll
        for (int i = 0; i < BLOCK / 64; ++i) t += smem[i];
        partial[blockIdx.x] = t;
    }
}

__global__ __launch_bounds__(256) void kl_final_kernel(
    const float* __restrict__ partial, float* __restrict__ out)
{
    float acc = 0.0f;
    for (int i = threadIdx.x; i < GRID; i += 256)
        acc += partial[i];

    #pragma unroll
    for (int off = 32; off > 0; off >>= 1)
        acc += __shfl_down(acc, off, 64);

    __shared__ float smem[4];
    const int lane = threadIdx.x & 63;
    const int wid  = threadIdx.x >> 6;
    if (lane == 0) smem[wid] = acc;
    __syncthreads();

    if (threadIdx.x == 0) {
        float t = 0.0f;
        #pragma unroll
        for (int w = 0; w < 4; ++w) t += smem[w];
        out[0] = t * INV_BL;
    }
}

extern "C" void kernel_launch(void* const* d_in, const int* in_sizes, int n_in,
                              void* d_out, int out_size, void* d_ws, size_t ws_size,
                              hipStream_t stream) {
    const float4* pm = (const float4*)d_in[0];  // prior_mu
    const float4* ps = (const float4*)d_in[1];  // prior_sigma
    const float4* qm = (const float4*)d_in[2];  // post_mu
    const float4* qs = (const float4*)d_in[3];  // post_sigma
    float* partial = (float*)d_ws;              // GRID floats = 4 KiB scratch
    float* out     = (float*)d_out;

    kl_partial_kernel<<<GRID, BLOCK, 0, stream>>>(pm, ps, qm, qs, partial);
    kl_final_kernel<<<1, 256, 0, stream>>>(partial, out);
}

// Round 7
// 146.266 us; speedup vs baseline: 1.3020x; 1.0342x over previous
//
#include <hip/hip_runtime.h>

// KL( N(pm, ps^2) || N(qm, qs^2) ) over [32,128,32,64], sum/(B*L).
// kl_elem = 0.5*(r^2 + d^2 - 1) - log(r),  r = ps/qs, d = (qm-pm)/qs.
//
// Evidence ledger:
//  R8: nt VGPR-loads, deep-32 -> partial 35.6us (3.77 TB/s). Best.
//  R9: occupancy 3->4 blocks/CU -> null.
//  R10: cached loads -> 43-47us; L3-warm replays (hbm~0) still 42us.
//  R11: last-block fusion -> +38us (serial atomic tail). Reverted.
//  R12/R13: DMA + asm counted-vmcnt, no barriers -> container wedged. Retired.
//  R14: DMA + __syncthreads (safe) -> 43-45us (3.1 TB/s), warm replays same.
//    => EVERY single path caps ~3.1-3.8 TB/s, tier-independent,
//       occupancy-independent. Cap is CU-side read-return machinery.
//  R15 (this round): run BOTH return paths concurrently on disjoint data:
//    chunks 5..7 via global_load_lds DMA (returns to LDS write port),
//    chunks 0..4 via nt VGPR loads (returns to VGPR writeback), one
//    __syncthreads drain between phases. If the caps are per-path, they
//    sum (~5+ TB/s); if shared upstream, null -> roofline.

constexpr int TOTAL  = 32 * 128 * 32 * 64;   // 8388608 elements
constexpr int N4     = TOTAL / 4;            // 2097152 float4 per array
constexpr int BLOCK  = 256;
constexpr int GRID   = 1024;
constexpr int TILE4  = N4 / GRID;            // 2048 float4 per array per block
constexpr int CH4    = 256;                  // float4 per chunk per array (block-wide)
constexpr int NCH    = TILE4 / CH4;          // 8 chunks
constexpr int NT_CH  = 5;                    // chunks via nt-VGPR path
constexpr int DMA_CH = 3;                    // chunks via global_load_lds path
constexpr float INV_BL = 1.0f / (32.0f * 128.0f);

static_assert(NCH == 8 && NT_CH + DMA_CH == NCH, "5/3 split, exact");

typedef float f4 __attribute__((ext_vector_type(4)));

__device__ __forceinline__ f4 ntload(const float4* p) {
    return __builtin_nontemporal_load((const f4*)p);
}

// global(as1) -> LDS(as3) DMA, 16B per lane. LDS dest is the wave-uniform
// base (HW adds lane*16); global src is per-lane. Size must be literal 16.
__device__ __forceinline__ void stage16(const float4* g, const float4* l) {
    __builtin_amdgcn_global_load_lds(
        (const __attribute__((address_space(1))) void*)g,
        (__attribute__((address_space(3))) void*)l,
        16, 0, 0);
}

__device__ __forceinline__ float kl_elem(float a, float b, float c, float d) {
    float inv = __builtin_amdgcn_rcpf(d);     // v_rcp_f32, ~1ulp (tol is 2%)
    float r   = b * inv;
    float df  = (c - a) * inv;
    return 0.5f * (r * r + df * df - 1.0f) - __logf(r);
}

__device__ __forceinline__ float kl_4(f4 a, f4 b, f4 c, f4 d) {
    return (kl_elem(a.x, b.x, c.x, d.x) + kl_elem(a.y, b.y, c.y, d.y))
         + (kl_elem(a.z, b.z, c.z, d.z) + kl_elem(a.w, b.w, c.w, d.w));
}

__global__ __launch_bounds__(BLOCK) void kl_partial_kernel(
    const float4* __restrict__ pm, const float4* __restrict__ ps,
    const float4* __restrict__ qm, const float4* __restrict__ qs,
    float* __restrict__ partial)
{
    __shared__ float4 lds[DMA_CH][4][CH4];   // 48 KB

    const int tid  = threadIdx.x;
    const int lane = tid & 63;
    const int w    = tid >> 6;               // wave id (wave-uniform)
    const int gbase = blockIdx.x * TILE4;    // block's float4 base index

    // ---- Phase 1: issue ALL DMA for the trailing 3 chunks (12/wave). ----
    // Wave w stages lds[dc][arr][w*64 .. w*64+64) -- exactly the region its
    // own lanes consume later (tid = w*64+lane). In flight during phase 2.
    #pragma unroll
    for (int dc = 0; dc < DMA_CH; ++dc) {
        const int idx = gbase + (NT_CH + dc) * CH4 + w * 64 + lane;
        stage16(pm + idx, &lds[dc][0][w * 64]);
        stage16(ps + idx, &lds[dc][1][w * 64]);
        stage16(qm + idx, &lds[dc][2][w * 64]);
        stage16(qs + idx, &lds[dc][3][w * 64]);
    }

    // ---- Phase 2: nt-VGPR path on the leading 5 chunks (R8 pattern). ----
    f4 A[NT_CH], Bv[NT_CH], C[NT_CH], Dv[NT_CH];
    #pragma unroll
    for (int j = 0; j < NT_CH; ++j) {
        const int i = gbase + j * CH4 + tid;
        A[j]  = ntload(pm + i);
        Bv[j] = ntload(ps + i);
        C[j]  = ntload(qm + i);
        Dv[j] = ntload(qs + i);
    }
    __builtin_amdgcn_sched_barrier(0);       // loads stay issued above

    float acc = 0.0f;
    #pragma unroll
    for (int j = 0; j < NT_CH; ++j)
        acc += kl_4(A[j], Bv[j], C[j], Dv[j]);

    // ---- Drain: compiler emits s_waitcnt vmcnt(0) before s_barrier,  ----
    // ---- so all DMA has landed in LDS. (R14-proven safe structure.)  ----
    __syncthreads();

    // ---- Phase 3: consume the DMA half from LDS (conflict-free b128). ----
    #pragma unroll
    for (int dc = 0; dc < DMA_CH; ++dc) {
        const f4 a  = *(const f4*)&lds[dc][0][tid];
        const f4 b  = *(const f4*)&lds[dc][1][tid];
        const f4 cc = *(const f4*)&lds[dc][2][tid];
        const f4 d  = *(const f4*)&lds[dc][3][tid];
        acc += kl_4(a, b, cc, d);
    }

    // wave-64 reduction
    #pragma unroll
    for (int off = 32; off > 0; off >>= 1)
        acc += __shfl_down(acc, off, 64);

    __shared__ float smem[BLOCK / 64];
    if (lane == 0) smem[w] = acc;
    __syncthreads();

    if (tid == 0) {
        float t = 0.0f;
        #pragma unroll
        for (int i = 0; i < BLOCK / 64; ++i) t += smem[i];
        partial[blockIdx.x] = t;
    }
}

__global__ __launch_bounds__(256) void kl_final_kernel(
    const float* __restrict__ partial, float* __restrict__ out)
{
    float acc = 0.0f;
    for (int i = threadIdx.x; i < GRID; i += 256)
        acc += partial[i];

    #pragma unroll
    for (int off = 32; off > 0; off >>= 1)
        acc += __shfl_down(acc, off, 64);

    __shared__ float smem[4];
    const int lane = threadIdx.x & 63;
    const int wid  = threadIdx.x >> 6;
    if (lane == 0) smem[wid] = acc;
    __syncthreads();

    if (threadIdx.x == 0) {
        float t = 0.0f;
        #pragma unroll
        for (int w = 0; w < 4; ++w) t += smem[w];
        out[0] = t * INV_BL;
    }
}

extern "C" void kernel_launch(void* const* d_in, const int* in_sizes, int n_in,
                              void* d_out, int out_size, void* d_ws, size_t ws_size,
                              hipStream_t stream) {
    const float4* pm = (const float4*)d_in[0];  // prior_mu
    const float4* ps = (const float4*)d_in[1];  // prior_sigma
    const float4* qm = (const float4*)d_in[2];  // post_mu
    const float4* qs = (const float4*)d_in[3];  // post_sigma
    float* partial = (float*)d_ws;              // GRID floats = 4 KiB scratch
    float* out     = (float*)d_out;

    kl_partial_kernel<<<GRID, BLOCK, 0, stream>>>(pm, ps, qm, qs, partial);
    kl_final_kernel<<<1, 256, 0, stream>>>(partial, out);
}

// Round 8
// 141.380 us; speedup vs baseline: 1.3470x; 1.0346x over previous
//
#include <hip/hip_runtime.h>

// KL( N(pm, ps^2) || N(qm, qs^2) ) over [32,128,32,64], sum/(B*L).
// kl_elem = 0.5*(r^2 + d^2 - 1) - log(r),  r = ps/qs, d = (qm-pm)/qs.
//
// FINAL (R16): revert to the proven-best R8 structure (141.3us total,
// partial 35.6us = 3.77 TB/s read). Session evidence ledger:
//  R9:  occupancy 3->4 blocks/CU -> null (residency not binding).
//  R10: cached loads -> slower (3.1 TB/s); L3-WARM replays (hbm~0)
//       identical -> cap is tier-INDEPENDENT.
//  R11: single-kernel last-block fusion -> +38us (serialized same-address
//       atomic tail across 1024 uniform-finish blocks). Reverted.
//  R12/R13: DMA + asm counted-vmcnt, barrier-free -> container wedged. Retired.
//  R14: global_load_lds DMA + __syncthreads -> 3.1 TB/s, warm replays same.
//  R15: nt-VGPR + DMA-LDS paths CONCURRENT on disjoint halves -> no sum
//       (146us total) -> paths share one upstream limiter.
// Conclusion: pure-read service rate caps at ~3.8 TB/s chip-wide
// (~6 B/cyc/CU), independent of tier, occupancy, depth, and return path.
// 134.2 MB / 3.8 TB/s ~= 35us floor; this kernel runs 35.6us (~99%).
// Writes (harness fills) reach 6.5 TB/s because they are posted; reads
// cannot. Remaining dur_us is harness fill/launch overhead.

constexpr int TOTAL  = 32 * 128 * 32 * 64;   // 8388608 elements
constexpr int N4     = TOTAL / 4;            // 2097152 float4 per array
constexpr int BLOCK  = 256;
constexpr int GRID   = 1024;
constexpr int TILE4  = N4 / GRID;            // 2048 float4 per array per block
constexpr int PT     = TILE4 / BLOCK;        // 8 batches per thread
constexpr float INV_BL = 1.0f / (32.0f * 128.0f);

static_assert(PT == 8, "depth-8 per-thread, exact");

typedef float f4 __attribute__((ext_vector_type(4)));

__device__ __forceinline__ f4 ntload(const float4* p) {
    return __builtin_nontemporal_load((const f4*)p);
}

__device__ __forceinline__ float kl_elem(float a, float b, float c, float d) {
    float inv = __builtin_amdgcn_rcpf(d);     // v_rcp_f32, ~1ulp (tol is 2%)
    float r   = b * inv;
    float df  = (c - a) * inv;
    return 0.5f * (r * r + df * df - 1.0f) - __logf(r);
}

__device__ __forceinline__ float kl_4(f4 a, f4 b, f4 c, f4 d) {
    return (kl_elem(a.x, b.x, c.x, d.x) + kl_elem(a.y, b.y, c.y, d.y))
         + (kl_elem(a.z, b.z, c.z, d.z) + kl_elem(a.w, b.w, c.w, d.w));
}

__global__ __launch_bounds__(BLOCK) void kl_partial_kernel(
    const float4* __restrict__ pm, const float4* __restrict__ ps,
    const float4* __restrict__ qm, const float4* __restrict__ qs,
    float* __restrict__ partial)
{
    const int base = blockIdx.x * TILE4 + threadIdx.x;

    // Issue ALL 32 nt loads, batch-major (consumption order == issue order).
    f4 A[PT], Bv[PT], C[PT], Dv[PT];
    #pragma unroll
    for (int j = 0; j < PT; ++j) {
        const int i = base + j * BLOCK;
        A[j]  = ntload(pm + i);
        Bv[j] = ntload(ps + i);
        C[j]  = ntload(qm + i);
        Dv[j] = ntload(qs + i);
    }

    // Hard fence: loads stay issued above; consumption below.
    __builtin_amdgcn_sched_barrier(0);

    float accA = 0.0f, accB = 0.0f;
    #pragma unroll
    for (int j = 0; j < PT; j += 2) {
        accA += kl_4(A[j],     Bv[j],     C[j],     Dv[j]);
        accB += kl_4(A[j + 1], Bv[j + 1], C[j + 1], Dv[j + 1]);
    }
    float acc = accA + accB;

    // wave-64 reduction
    #pragma unroll
    for (int off = 32; off > 0; off >>= 1)
        acc += __shfl_down(acc, off, 64);

    __shared__ float smem[BLOCK / 64];
    const int lane = threadIdx.x & 63;
    const int wid  = threadIdx.x >> 6;
    if (lane == 0) smem[wid] = acc;
    __syncthreads();

    if (threadIdx.x == 0) {
        float t = 0.0f;
        #pragma unroll
        for (int w = 0; w < BLOCK / 64; ++w) t += smem[w];
        partial[blockIdx.x] = t;
    }
}

__global__ __launch_bounds__(256) void kl_final_kernel(
    const float* __restrict__ partial, float* __restrict__ out)
{
    float acc = 0.0f;
    for (int i = threadIdx.x; i < GRID; i += 256)
        acc += partial[i];

    #pragma unroll
    for (int off = 32; off > 0; off >>= 1)
        acc += __shfl_down(acc, off, 64);

    __shared__ float smem[4];
    const int lane = threadIdx.x & 63;
    const int wid  = threadIdx.x >> 6;
    if (lane == 0) smem[wid] = acc;
    __syncthreads();

    if (threadIdx.x == 0) {
        float t = 0.0f;
        #pragma unroll
        for (int w = 0; w < 4; ++w) t += smem[w];
        out[0] = t * INV_BL;
    }
}

extern "C" void kernel_launch(void* const* d_in, const int* in_sizes, int n_in,
                              void* d_out, int out_size, void* d_ws, size_t ws_size,
                              hipStream_t stream) {
    const float4* pm = (const float4*)d_in[0];  // prior_mu
    const float4* ps = (const float4*)d_in[1];  // prior_sigma
    const float4* qm = (const float4*)d_in[2];  // post_mu
    const float4* qs = (const float4*)d_in[3];  // post_sigma
    float* partial = (float*)d_ws;              // GRID floats = 4 KiB scratch
    float* out     = (float*)d_out;

    kl_partial_kernel<<<GRID, BLOCK, 0, stream>>>(pm, ps, qm, qs, partial);
    kl_final_kernel<<<1, 256, 0, stream>>>(partial, out);
}